// Round 6
// baseline (117.286 us; speedup 1.0000x reference)
//
#include <hip/hip_runtime.h>
#include <hip/hip_bf16.h>
#include <math.h>

// Problem constants (reference: BATCH=2048, D=256, TEMP=0.5)
#define NB      2048
#define TWO_N   4096
#define DIM     256
#define EPS     1e-12f
#define NTILES  32                            // 4096 / 128
#define NBLK    (NTILES * (NTILES + 1) / 2)   // 528 triangle tiles

typedef __attribute__((ext_vector_type(8))) short  bf16x8;   // 8 bf16 = 4 VGPRs
typedef __attribute__((ext_vector_type(4))) float  f32x4;    // MFMA C/D

// ---------------------------------------------------------------------------
// K1: one wave per PAIR r in [0,2048): L2-normalize emb_i[r] -> z[r] and
// emb_j[r] -> z[r+NB] (bf16), and write the fp32-exact positive dot
// pos[r] = <z_i, z_j>. Also zeroes den[4096] and the ticket counter.
// ---------------------------------------------------------------------------
__global__ __launch_bounds__(256) void nrm_kernel(
    const float* __restrict__ emb_i, const float* __restrict__ emb_j,
    __hip_bfloat16* __restrict__ zb, float* __restrict__ pos,
    float* __restrict__ den, unsigned* __restrict__ cnt)
{
    int t = threadIdx.x;
    int wave = t >> 6, lane = t & 63;
    int r = blockIdx.x * 4 + wave;              // pair index 0..2047
    float4 a = ((const float4*)(emb_i + (size_t)r * DIM))[lane];
    float4 b = ((const float4*)(emb_j + (size_t)r * DIM))[lane];
    float sa = a.x*a.x + a.y*a.y + a.z*a.z + a.w*a.w;
    float sb = b.x*b.x + b.y*b.y + b.z*b.z + b.w*b.w;
    float sd = a.x*b.x + a.y*b.y + a.z*b.z + a.w*b.w;
    #pragma unroll
    for (int off = 32; off >= 1; off >>= 1) {
        sa += __shfl_xor(sa, off, 64);
        sb += __shfl_xor(sb, off, 64);
        sd += __shfl_xor(sd, off, 64);
    }
    float si = 1.0f / fmaxf(sqrtf(sa), EPS);
    float sj = 1.0f / fmaxf(sqrtf(sb), EPS);

    union { __hip_bfloat16 h[4]; uint2 u; } pk;
    pk.h[0] = __float2bfloat16(a.x * si);
    pk.h[1] = __float2bfloat16(a.y * si);
    pk.h[2] = __float2bfloat16(a.z * si);
    pk.h[3] = __float2bfloat16(a.w * si);
    ((uint2*)(zb + (size_t)r * DIM))[lane] = pk.u;
    pk.h[0] = __float2bfloat16(b.x * sj);
    pk.h[1] = __float2bfloat16(b.y * sj);
    pk.h[2] = __float2bfloat16(b.z * sj);
    pk.h[3] = __float2bfloat16(b.w * sj);
    ((uint2*)(zb + (size_t)(r + NB) * DIM))[lane] = pk.u;

    if (lane == 0) pos[r] = sd * si * sj;
    if (t < 8) den[blockIdx.x * 8 + t] = 0.0f;  // 512 blocks x 8 = 4096
    if (blockIdx.x == 0 && t == 0) *cnt = 0u;
}

// ---------------------------------------------------------------------------
// K2: den[r] += sum_j exp(2 * z_r . z_j) via bf16 MFMA, symmetric: 1-D grid
// of exactly the 528 upper-triangle 128x128 tiles (id = by*(by+1)/2 + bx).
// Off-diagonal blocks scatter both row-sums and col-sums into den.
// 4 waves in 2x2; wave tile 64x64 = 4x4 MFMA 16x16x32 accumulators.
// K-loop register double-buffered, fragments straight from L2 (no LDS).
// Tail: last-block-done (threadfence + ticket) computes the final loss:
// out = (sum_r log(den[r]) - 4 * sum_p pos[p]) / 4096.  No 3rd launch.
// Fragment layouts (verified m89/m91): A[m=lane&15][k=quad*8+j],
// B[k=quad*8+j][n=lane&15], C/D: col=lane&15, row=quad*4+reg.
// ---------------------------------------------------------------------------
__global__ __launch_bounds__(256, 3) void simexp_kernel(
    const __hip_bfloat16* __restrict__ zb, const float* __restrict__ pos,
    float* __restrict__ den, unsigned* __restrict__ cnt,
    float* __restrict__ out)
{
    // Decode linear triangle index -> (bx, by), bx <= by.
    int id = blockIdx.x;
    int by = (int)((sqrtf(8.0f * (float)id + 1.0f) - 1.0f) * 0.5f);
    while ((by + 1) * (by + 2) / 2 <= id) ++by;   // fix float rounding
    while (by * (by + 1) / 2 > id) --by;
    int bx = id - by * (by + 1) / 2;

    const short* Z = (const short*)zb;
    int t = threadIdx.x;
    int w = t >> 6, lane = t & 63;
    int quad = lane >> 4, c16 = lane & 15;
    int wm = w >> 1, wn = w & 1;
    int rbase = bx * 128 + wm * 64;
    int jbase = by * 128 + wn * 64;

    const short* ap[4];
    const short* bp[4];
    #pragma unroll
    for (int mt = 0; mt < 4; ++mt)
        ap[mt] = Z + (size_t)(rbase + mt * 16 + c16) * DIM + quad * 8;
    #pragma unroll
    for (int nt = 0; nt < 4; ++nt)
        bp[nt] = Z + (size_t)(jbase + nt * 16 + c16) * DIM + quad * 8;

    f32x4 acc[4][4];
    #pragma unroll
    for (int mt = 0; mt < 4; ++mt)
        #pragma unroll
        for (int nt = 0; nt < 4; ++nt)
            acc[mt][nt] = (f32x4){0.f, 0.f, 0.f, 0.f};

    // Register double-buffered K loop: load kk+1 while MFMAing kk.
    bf16x8 af[2][4], bfv[2][4];
    #pragma unroll
    for (int mt = 0; mt < 4; ++mt) af[0][mt] = *(const bf16x8*)(ap[mt]);
    #pragma unroll
    for (int nt = 0; nt < 4; ++nt) bfv[0][nt] = *(const bf16x8*)(bp[nt]);

    #pragma unroll
    for (int kk = 0; kk < 8; ++kk) {
        int cur = kk & 1, nxt = cur ^ 1;
        if (kk < 7) {
            #pragma unroll
            for (int mt = 0; mt < 4; ++mt)
                af[nxt][mt] = *(const bf16x8*)(ap[mt] + (kk + 1) * 32);
            #pragma unroll
            for (int nt = 0; nt < 4; ++nt)
                bfv[nxt][nt] = *(const bf16x8*)(bp[nt] + (kk + 1) * 32);
        }
        #pragma unroll
        for (int mt = 0; mt < 4; ++mt)
            #pragma unroll
            for (int nt = 0; nt < 4; ++nt)
                acc[mt][nt] = __builtin_amdgcn_mfma_f32_16x16x32_bf16(
                    af[cur][mt], bfv[cur][nt], acc[mt][nt], 0, 0, 0);
    }

    // Epilogue. Row of acc[mt][nt][rg] = rbase+mt*16+quad*4+rg,
    // col = jbase+nt*16+c16.
    float rsum[4][4];
    #pragma unroll
    for (int mt = 0; mt < 4; ++mt)
        #pragma unroll
        for (int rg = 0; rg < 4; ++rg) rsum[mt][rg] = 0.f;

    if (bx == by) {
        // Diagonal block: mask r==j, row-sums only.
        #pragma unroll
        for (int mt = 0; mt < 4; ++mt) {
            #pragma unroll
            for (int nt = 0; nt < 4; ++nt) {
                int j = jbase + nt * 16 + c16;
                #pragma unroll
                for (int rg = 0; rg < 4; ++rg) {
                    int r = rbase + mt * 16 + quad * 4 + rg;
                    float e = __expf(2.0f * acc[mt][nt][rg]);
                    rsum[mt][rg] += (r == j) ? 0.f : e;
                }
            }
        }
    } else {
        // Off-diagonal: no diagonal possible; row-sums AND col-sums.
        float csum[4] = {0.f, 0.f, 0.f, 0.f};
        #pragma unroll
        for (int mt = 0; mt < 4; ++mt) {
            #pragma unroll
            for (int nt = 0; nt < 4; ++nt) {
                #pragma unroll
                for (int rg = 0; rg < 4; ++rg) {
                    float e = __expf(2.0f * acc[mt][nt][rg]);
                    rsum[mt][rg] += e;
                    csum[nt] += e;
                }
            }
        }
        // col c16 of tile nt: sum the 4 quads, atomic from quad 0.
        #pragma unroll
        for (int nt = 0; nt < 4; ++nt) {
            float v = csum[nt];
            v += __shfl_xor(v, 16, 64);
            v += __shfl_xor(v, 32, 64);
            if (quad == 0)
                atomicAdd(&den[jbase + nt * 16 + c16], v);
        }
    }

    // Row-sums: reduce the 16 col-lanes of each quad, atomic from c16==0.
    #pragma unroll
    for (int mt = 0; mt < 4; ++mt) {
        #pragma unroll
        for (int rg = 0; rg < 4; ++rg) {
            float v = rsum[mt][rg];
            v += __shfl_xor(v, 1, 64);
            v += __shfl_xor(v, 2, 64);
            v += __shfl_xor(v, 4, 64);
            v += __shfl_xor(v, 8, 64);
            if (c16 == 0)
                atomicAdd(&den[rbase + mt * 16 + quad * 4 + rg], v);
        }
    }

    // ------------- last-block-done: final loss reduction -------------------
    __threadfence();                            // den atomics visible first
    __shared__ bool last;
    if (t == 0)
        last = (atomicAdd(cnt, 1u) == NBLK - 1);
    __syncthreads();
    if (!last) return;

    __threadfence();                            // acquire: see all den writes
    __shared__ float red[4];
    float s = 0.f;
    for (int r = t; r < TWO_N; r += 256) {
        float d = __hip_atomic_load(&den[r], __ATOMIC_RELAXED,
                                    __HIP_MEMORY_SCOPE_AGENT);
        s += logf(d);
    }
    for (int p = t; p < NB; p += 256) s -= 4.0f * pos[p];
    #pragma unroll
    for (int off = 32; off >= 1; off >>= 1) s += __shfl_xor(s, off, 64);
    if ((t & 63) == 0) red[t >> 6] = s;
    __syncthreads();
    if (t == 0)
        out[0] = (red[0] + red[1] + red[2] + red[3]) * (1.0f / (float)TWO_N);
}

// ---------------------------------------------------------------------------
extern "C" void kernel_launch(void* const* d_in, const int* in_sizes, int n_in,
                              void* d_out, int out_size, void* d_ws, size_t ws_size,
                              hipStream_t stream)
{
    const float* emb_i = (const float*)d_in[0];
    const float* emb_j = (const float*)d_in[1];
    float* out = (float*)d_out;

    __hip_bfloat16* zb = (__hip_bfloat16*)d_ws;           // 4096*256 bf16 = 2 MB
    float* den = (float*)((char*)d_ws + (size_t)TWO_N * DIM * sizeof(__hip_bfloat16));
    float* pos = den + TWO_N;                             // 2048 f32
    unsigned* cnt = (unsigned*)(pos + NB);                // 1 u32 ticket

    nrm_kernel<<<NB / 4, 256, 0, stream>>>(emb_i, emb_j, zb, pos, den, cnt);

    simexp_kernel<<<NBLK, 256, 0, stream>>>(zb, pos, den, cnt, out);
}

// Round 7
// 104.373 us; speedup vs baseline: 1.1237x; 1.1237x over previous
//
#include <hip/hip_runtime.h>
#include <hip/hip_bf16.h>
#include <math.h>

// Problem constants (reference: BATCH=2048, D=256, TEMP=0.5)
#define NB      2048
#define TWO_N   4096
#define DIM     256
#define EPS     1e-12f
#define NTILES  32                            // 4096 / 128
#define NBLK    (NTILES * (NTILES + 1) / 2)   // 528 triangle tiles

typedef __attribute__((ext_vector_type(8))) short  bf16x8;   // 8 bf16 = 4 VGPRs
typedef __attribute__((ext_vector_type(4))) float  f32x4;    // MFMA C/D

// ---------------------------------------------------------------------------
// K1: one wave per PAIR r in [0,2048): L2-normalize emb_i[r] -> z[r] and
// emb_j[r] -> z[r+NB] (bf16), and write the fp32-exact positive dot
// pos[r] = <z_i, z_j>. Also zeroes den[4096] and the ticket counter.
// ---------------------------------------------------------------------------
__global__ __launch_bounds__(256) void nrm_kernel(
    const float* __restrict__ emb_i, const float* __restrict__ emb_j,
    __hip_bfloat16* __restrict__ zb, float* __restrict__ pos,
    float* __restrict__ den, unsigned* __restrict__ cnt)
{
    int t = threadIdx.x;
    int wave = t >> 6, lane = t & 63;
    int r = blockIdx.x * 4 + wave;              // pair index 0..2047
    float4 a = ((const float4*)(emb_i + (size_t)r * DIM))[lane];
    float4 b = ((const float4*)(emb_j + (size_t)r * DIM))[lane];
    float sa = a.x*a.x + a.y*a.y + a.z*a.z + a.w*a.w;
    float sb = b.x*b.x + b.y*b.y + b.z*b.z + b.w*b.w;
    float sd = a.x*b.x + a.y*b.y + a.z*b.z + a.w*b.w;
    #pragma unroll
    for (int off = 32; off >= 1; off >>= 1) {
        sa += __shfl_xor(sa, off, 64);
        sb += __shfl_xor(sb, off, 64);
        sd += __shfl_xor(sd, off, 64);
    }
    float si = 1.0f / fmaxf(sqrtf(sa), EPS);
    float sj = 1.0f / fmaxf(sqrtf(sb), EPS);

    union { __hip_bfloat16 h[4]; uint2 u; } pk;
    pk.h[0] = __float2bfloat16(a.x * si);
    pk.h[1] = __float2bfloat16(a.y * si);
    pk.h[2] = __float2bfloat16(a.z * si);
    pk.h[3] = __float2bfloat16(a.w * si);
    ((uint2*)(zb + (size_t)r * DIM))[lane] = pk.u;
    pk.h[0] = __float2bfloat16(b.x * sj);
    pk.h[1] = __float2bfloat16(b.y * sj);
    pk.h[2] = __float2bfloat16(b.z * sj);
    pk.h[3] = __float2bfloat16(b.w * sj);
    ((uint2*)(zb + (size_t)(r + NB) * DIM))[lane] = pk.u;

    if (lane == 0) pos[r] = sd * si * sj;
    if (t < 8) den[blockIdx.x * 8 + t] = 0.0f;  // 512 blocks x 8 = 4096
    if (blockIdx.x == 0 && t == 0) *cnt = 0u;
}

// ---------------------------------------------------------------------------
// K2: den[r] += sum_j exp(2 * z_r . z_j) via bf16 MFMA, symmetric: 1-D grid
// of exactly the 528 upper-triangle 128x128 tiles (id = by*(by+1)/2 + bx).
// Off-diagonal blocks scatter both row-sums and col-sums into den.
// 4 waves in 2x2; wave tile 64x64 = 4x4 MFMA 16x16x32 accumulators.
// K-loop register double-buffered, fragments straight from L2 (no LDS).
// Tail: last-block-done ticket computes the final loss in this kernel.
// SYNC NOTE (R6 post-mortem): NO seq_cst __threadfence() here — on gfx950
// that emits buffer_inv sc1 (full per-XCD L2 invalidate) in every block,
// which evicted z mid-flight for running blocks (62 us regression). Release
// fence (waitcnt+wbl2, no inv) for all blocks; acquire fence only in the
// single last block.
// ---------------------------------------------------------------------------
__global__ __launch_bounds__(256, 3) void simexp_kernel(
    const __hip_bfloat16* __restrict__ zb, const float* __restrict__ pos,
    float* __restrict__ den, unsigned* __restrict__ cnt,
    float* __restrict__ out)
{
    // Decode linear triangle index -> (bx, by), bx <= by.
    int id = blockIdx.x;
    int by = (int)((sqrtf(8.0f * (float)id + 1.0f) - 1.0f) * 0.5f);
    while ((by + 1) * (by + 2) / 2 <= id) ++by;   // fix float rounding
    while (by * (by + 1) / 2 > id) --by;
    int bx = id - by * (by + 1) / 2;

    const short* Z = (const short*)zb;
    int t = threadIdx.x;
    int w = t >> 6, lane = t & 63;
    int quad = lane >> 4, c16 = lane & 15;
    int wm = w >> 1, wn = w & 1;
    int rbase = bx * 128 + wm * 64;
    int jbase = by * 128 + wn * 64;

    const short* ap[4];
    const short* bp[4];
    #pragma unroll
    for (int mt = 0; mt < 4; ++mt)
        ap[mt] = Z + (size_t)(rbase + mt * 16 + c16) * DIM + quad * 8;
    #pragma unroll
    for (int nt = 0; nt < 4; ++nt)
        bp[nt] = Z + (size_t)(jbase + nt * 16 + c16) * DIM + quad * 8;

    f32x4 acc[4][4];
    #pragma unroll
    for (int mt = 0; mt < 4; ++mt)
        #pragma unroll
        for (int nt = 0; nt < 4; ++nt)
            acc[mt][nt] = (f32x4){0.f, 0.f, 0.f, 0.f};

    // Register double-buffered K loop: load kk+1 while MFMAing kk.
    bf16x8 af[2][4], bfv[2][4];
    #pragma unroll
    for (int mt = 0; mt < 4; ++mt) af[0][mt] = *(const bf16x8*)(ap[mt]);
    #pragma unroll
    for (int nt = 0; nt < 4; ++nt) bfv[0][nt] = *(const bf16x8*)(bp[nt]);

    #pragma unroll
    for (int kk = 0; kk < 8; ++kk) {
        int cur = kk & 1, nxt = cur ^ 1;
        if (kk < 7) {
            #pragma unroll
            for (int mt = 0; mt < 4; ++mt)
                af[nxt][mt] = *(const bf16x8*)(ap[mt] + (kk + 1) * 32);
            #pragma unroll
            for (int nt = 0; nt < 4; ++nt)
                bfv[nxt][nt] = *(const bf16x8*)(bp[nt] + (kk + 1) * 32);
        }
        #pragma unroll
        for (int mt = 0; mt < 4; ++mt)
            #pragma unroll
            for (int nt = 0; nt < 4; ++nt)
                acc[mt][nt] = __builtin_amdgcn_mfma_f32_16x16x32_bf16(
                    af[cur][mt], bfv[cur][nt], acc[mt][nt], 0, 0, 0);
    }

    // Epilogue. Row of acc[mt][nt][rg] = rbase+mt*16+quad*4+rg,
    // col = jbase+nt*16+c16.
    float rsum[4][4];
    #pragma unroll
    for (int mt = 0; mt < 4; ++mt)
        #pragma unroll
        for (int rg = 0; rg < 4; ++rg) rsum[mt][rg] = 0.f;

    if (bx == by) {
        // Diagonal block: mask r==j, row-sums only.
        #pragma unroll
        for (int mt = 0; mt < 4; ++mt) {
            #pragma unroll
            for (int nt = 0; nt < 4; ++nt) {
                int j = jbase + nt * 16 + c16;
                #pragma unroll
                for (int rg = 0; rg < 4; ++rg) {
                    int r = rbase + mt * 16 + quad * 4 + rg;
                    float e = __expf(2.0f * acc[mt][nt][rg]);
                    rsum[mt][rg] += (r == j) ? 0.f : e;
                }
            }
        }
    } else {
        // Off-diagonal: no diagonal possible; row-sums AND col-sums.
        float csum[4] = {0.f, 0.f, 0.f, 0.f};
        #pragma unroll
        for (int mt = 0; mt < 4; ++mt) {
            #pragma unroll
            for (int nt = 0; nt < 4; ++nt) {
                #pragma unroll
                for (int rg = 0; rg < 4; ++rg) {
                    float e = __expf(2.0f * acc[mt][nt][rg]);
                    rsum[mt][rg] += e;
                    csum[nt] += e;
                }
            }
        }
        // col c16 of tile nt: sum the 4 quads, atomic from quad 0.
        #pragma unroll
        for (int nt = 0; nt < 4; ++nt) {
            float v = csum[nt];
            v += __shfl_xor(v, 16, 64);
            v += __shfl_xor(v, 32, 64);
            if (quad == 0)
                atomicAdd(&den[jbase + nt * 16 + c16], v);
        }
    }

    // Row-sums: reduce the 16 col-lanes of each quad, atomic from c16==0.
    #pragma unroll
    for (int mt = 0; mt < 4; ++mt) {
        #pragma unroll
        for (int rg = 0; rg < 4; ++rg) {
            float v = rsum[mt][rg];
            v += __shfl_xor(v, 1, 64);
            v += __shfl_xor(v, 2, 64);
            v += __shfl_xor(v, 4, 64);
            v += __shfl_xor(v, 8, 64);
            if (c16 == 0)
                atomicAdd(&den[rbase + mt * 16 + quad * 4 + rg], v);
        }
    }

    // ------------- last-block-done: final loss reduction -------------------
    // Release: waitcnt + L2 writeback only (den adds are agent-scope atomics
    // already at the coherence point; nearly nothing dirty in L2). No inv.
    __builtin_amdgcn_fence(__ATOMIC_RELEASE, "agent");
    __shared__ bool last;
    if (t == 0)
        last = (__hip_atomic_fetch_add(cnt, 1u, __ATOMIC_RELAXED,
                                       __HIP_MEMORY_SCOPE_AGENT) == NBLK - 1);
    __syncthreads();
    if (!last) return;

    // Acquire in ONE block only (single L2 inv on this CU's XCD — harmless).
    __builtin_amdgcn_fence(__ATOMIC_ACQUIRE, "agent");
    __shared__ float red[4];
    float s = 0.f;
    for (int r = t; r < TWO_N; r += 256) {
        float d = __hip_atomic_load(&den[r], __ATOMIC_RELAXED,
                                    __HIP_MEMORY_SCOPE_AGENT);
        s += logf(d);
    }
    for (int p = t; p < NB; p += 256) s -= 4.0f * pos[p];
    #pragma unroll
    for (int off = 32; off >= 1; off >>= 1) s += __shfl_xor(s, off, 64);
    if ((t & 63) == 0) red[t >> 6] = s;
    __syncthreads();
    if (t == 0)
        out[0] = (red[0] + red[1] + red[2] + red[3]) * (1.0f / (float)TWO_N);
}

// ---------------------------------------------------------------------------
extern "C" void kernel_launch(void* const* d_in, const int* in_sizes, int n_in,
                              void* d_out, int out_size, void* d_ws, size_t ws_size,
                              hipStream_t stream)
{
    const float* emb_i = (const float*)d_in[0];
    const float* emb_j = (const float*)d_in[1];
    float* out = (float*)d_out;

    __hip_bfloat16* zb = (__hip_bfloat16*)d_ws;           // 4096*256 bf16 = 2 MB
    float* den = (float*)((char*)d_ws + (size_t)TWO_N * DIM * sizeof(__hip_bfloat16));
    float* pos = den + TWO_N;                             // 2048 f32
    unsigned* cnt = (unsigned*)(pos + NB);                // 1 u32 ticket

    nrm_kernel<<<NB / 4, 256, 0, stream>>>(emb_i, emb_j, zb, pos, den, cnt);

    simexp_kernel<<<NBLK, 256, 0, stream>>>(zb, pos, den, cnt, out);
}

// Round 8
// 94.433 us; speedup vs baseline: 1.2420x; 1.1053x over previous
//
#include <hip/hip_runtime.h>
#include <hip/hip_bf16.h>
#include <math.h>

// Problem constants (reference: BATCH=2048, D=256, TEMP=0.5)
#define NB      2048
#define TWO_N   4096
#define DIM     256
#define EPS     1e-12f
#define NTILES  32                            // 4096 / 128
#define NBLK    (NTILES * (NTILES + 1) / 2)   // 528 triangle tiles

typedef __attribute__((ext_vector_type(8))) short  bf16x8;   // 8 bf16 = 4 VGPRs
typedef __attribute__((ext_vector_type(4))) float  f32x4;    // MFMA C/D

// ---------------------------------------------------------------------------
// K1: one wave per PAIR r in [0,2048): L2-normalize emb_i[r] -> z[r] and
// emb_j[r] -> z[r+NB] (bf16), and write the fp32-exact positive dot
// pos[r] = <z_i, z_j>. Also zeroes den[4096] and the ticket counter.
// ---------------------------------------------------------------------------
__global__ __launch_bounds__(256) void nrm_kernel(
    const float* __restrict__ emb_i, const float* __restrict__ emb_j,
    __hip_bfloat16* __restrict__ zb, float* __restrict__ pos,
    float* __restrict__ den, unsigned* __restrict__ cnt)
{
    int t = threadIdx.x;
    int wave = t >> 6, lane = t & 63;
    int r = blockIdx.x * 4 + wave;              // pair index 0..2047
    float4 a = ((const float4*)(emb_i + (size_t)r * DIM))[lane];
    float4 b = ((const float4*)(emb_j + (size_t)r * DIM))[lane];
    float sa = a.x*a.x + a.y*a.y + a.z*a.z + a.w*a.w;
    float sb = b.x*b.x + b.y*b.y + b.z*b.z + b.w*b.w;
    float sd = a.x*b.x + a.y*b.y + a.z*b.z + a.w*b.w;
    #pragma unroll
    for (int off = 32; off >= 1; off >>= 1) {
        sa += __shfl_xor(sa, off, 64);
        sb += __shfl_xor(sb, off, 64);
        sd += __shfl_xor(sd, off, 64);
    }
    float si = 1.0f / fmaxf(sqrtf(sa), EPS);
    float sj = 1.0f / fmaxf(sqrtf(sb), EPS);

    union { __hip_bfloat16 h[4]; uint2 u; } pk;
    pk.h[0] = __float2bfloat16(a.x * si);
    pk.h[1] = __float2bfloat16(a.y * si);
    pk.h[2] = __float2bfloat16(a.z * si);
    pk.h[3] = __float2bfloat16(a.w * si);
    ((uint2*)(zb + (size_t)r * DIM))[lane] = pk.u;
    pk.h[0] = __float2bfloat16(b.x * sj);
    pk.h[1] = __float2bfloat16(b.y * sj);
    pk.h[2] = __float2bfloat16(b.z * sj);
    pk.h[3] = __float2bfloat16(b.w * sj);
    ((uint2*)(zb + (size_t)(r + NB) * DIM))[lane] = pk.u;

    if (lane == 0) pos[r] = sd * si * sj;
    if (t < 8) den[blockIdx.x * 8 + t] = 0.0f;  // 512 blocks x 8 = 4096
    if (blockIdx.x == 0 && t == 0) *cnt = 0u;
}

// ---------------------------------------------------------------------------
// K2: den[r] += sum_j exp(2 * z_r . z_j) via bf16 MFMA, symmetric: 1-D grid
// of exactly the 528 upper-triangle 128x128 tiles (id = by*(by+1)/2 + bx).
// Off-diagonal blocks scatter both row-sums and col-sums into den.
// 4 waves in 2x2; wave tile 64x64 = 4x4 MFMA 16x16x32 accumulators.
// K-loop register double-buffered, fragments straight from L2 (no LDS).
// Tail: last-block-done ticket computes the final loss in this kernel.
//
// SYNC NOTE (R6+R7 post-mortems): NO fences here at all.
//  - seq_cst __threadfence() per block  -> buffer_inv sc1 (L2 invalidate)
//    evicted z for running blocks: 62 us.
//  - release-agent builtin fence per block -> buffer_wbl2 sc1 (full L2
//    writeback walk) serialized block turnover: 48 us, WRITE_SIZE 2.6 MB.
// Correctness without fences: den/cnt adds are DEVICE-SCOPE atomics (gfx950
// default, coherence-point-operating, nothing dirty in per-XCD L2), and
// __syncthreads() already drains vmcnt(0) before its s_barrier, so this
// block's den-adds are performed-at-memory before the ticket add. The last
// block reads den with agent-scope atomic loads (coherence-point reads).
// ---------------------------------------------------------------------------
__global__ __launch_bounds__(256, 3) void simexp_kernel(
    const __hip_bfloat16* __restrict__ zb, const float* __restrict__ pos,
    float* __restrict__ den, unsigned* __restrict__ cnt,
    float* __restrict__ out)
{
    // Decode linear triangle index -> (bx, by), bx <= by.
    int id = blockIdx.x;
    int by = (int)((sqrtf(8.0f * (float)id + 1.0f) - 1.0f) * 0.5f);
    while ((by + 1) * (by + 2) / 2 <= id) ++by;   // fix float rounding
    while (by * (by + 1) / 2 > id) --by;
    int bx = id - by * (by + 1) / 2;

    const short* Z = (const short*)zb;
    int t = threadIdx.x;
    int w = t >> 6, lane = t & 63;
    int quad = lane >> 4, c16 = lane & 15;
    int wm = w >> 1, wn = w & 1;
    int rbase = bx * 128 + wm * 64;
    int jbase = by * 128 + wn * 64;

    const short* ap[4];
    const short* bp[4];
    #pragma unroll
    for (int mt = 0; mt < 4; ++mt)
        ap[mt] = Z + (size_t)(rbase + mt * 16 + c16) * DIM + quad * 8;
    #pragma unroll
    for (int nt = 0; nt < 4; ++nt)
        bp[nt] = Z + (size_t)(jbase + nt * 16 + c16) * DIM + quad * 8;

    f32x4 acc[4][4];
    #pragma unroll
    for (int mt = 0; mt < 4; ++mt)
        #pragma unroll
        for (int nt = 0; nt < 4; ++nt)
            acc[mt][nt] = (f32x4){0.f, 0.f, 0.f, 0.f};

    // Register double-buffered K loop: load kk+1 while MFMAing kk.
    bf16x8 af[2][4], bfv[2][4];
    #pragma unroll
    for (int mt = 0; mt < 4; ++mt) af[0][mt] = *(const bf16x8*)(ap[mt]);
    #pragma unroll
    for (int nt = 0; nt < 4; ++nt) bfv[0][nt] = *(const bf16x8*)(bp[nt]);

    #pragma unroll
    for (int kk = 0; kk < 8; ++kk) {
        int cur = kk & 1, nxt = cur ^ 1;
        if (kk < 7) {
            #pragma unroll
            for (int mt = 0; mt < 4; ++mt)
                af[nxt][mt] = *(const bf16x8*)(ap[mt] + (kk + 1) * 32);
            #pragma unroll
            for (int nt = 0; nt < 4; ++nt)
                bfv[nxt][nt] = *(const bf16x8*)(bp[nt] + (kk + 1) * 32);
        }
        #pragma unroll
        for (int mt = 0; mt < 4; ++mt)
            #pragma unroll
            for (int nt = 0; nt < 4; ++nt)
                acc[mt][nt] = __builtin_amdgcn_mfma_f32_16x16x32_bf16(
                    af[cur][mt], bfv[cur][nt], acc[mt][nt], 0, 0, 0);
    }

    // Epilogue. Row of acc[mt][nt][rg] = rbase+mt*16+quad*4+rg,
    // col = jbase+nt*16+c16.
    float rsum[4][4];
    #pragma unroll
    for (int mt = 0; mt < 4; ++mt)
        #pragma unroll
        for (int rg = 0; rg < 4; ++rg) rsum[mt][rg] = 0.f;

    if (bx == by) {
        // Diagonal block: mask r==j, row-sums only.
        #pragma unroll
        for (int mt = 0; mt < 4; ++mt) {
            #pragma unroll
            for (int nt = 0; nt < 4; ++nt) {
                int j = jbase + nt * 16 + c16;
                #pragma unroll
                for (int rg = 0; rg < 4; ++rg) {
                    int r = rbase + mt * 16 + quad * 4 + rg;
                    float e = __expf(2.0f * acc[mt][nt][rg]);
                    rsum[mt][rg] += (r == j) ? 0.f : e;
                }
            }
        }
    } else {
        // Off-diagonal: no diagonal possible; row-sums AND col-sums.
        float csum[4] = {0.f, 0.f, 0.f, 0.f};
        #pragma unroll
        for (int mt = 0; mt < 4; ++mt) {
            #pragma unroll
            for (int nt = 0; nt < 4; ++nt) {
                #pragma unroll
                for (int rg = 0; rg < 4; ++rg) {
                    float e = __expf(2.0f * acc[mt][nt][rg]);
                    rsum[mt][rg] += e;
                    csum[nt] += e;
                }
            }
        }
        // col c16 of tile nt: sum the 4 quads, atomic from quad 0.
        #pragma unroll
        for (int nt = 0; nt < 4; ++nt) {
            float v = csum[nt];
            v += __shfl_xor(v, 16, 64);
            v += __shfl_xor(v, 32, 64);
            if (quad == 0)
                atomicAdd(&den[jbase + nt * 16 + c16], v);
        }
    }

    // Row-sums: reduce the 16 col-lanes of each quad, atomic from c16==0.
    #pragma unroll
    for (int mt = 0; mt < 4; ++mt) {
        #pragma unroll
        for (int rg = 0; rg < 4; ++rg) {
            float v = rsum[mt][rg];
            v += __shfl_xor(v, 1, 64);
            v += __shfl_xor(v, 2, 64);
            v += __shfl_xor(v, 4, 64);
            v += __shfl_xor(v, 8, 64);
            if (c16 == 0)
                atomicAdd(&den[rbase + mt * 16 + quad * 4 + rg], v);
        }
    }

    // ------------- last-block-done: final loss reduction -------------------
    // __syncthreads() drains vmcnt(0) -> this block's den atomics are
    // performed at the coherence point before the ticket add below.
    __shared__ bool last;
    __syncthreads();
    if (t == 0)
        last = (__hip_atomic_fetch_add(cnt, 1u, __ATOMIC_RELAXED,
                                       __HIP_MEMORY_SCOPE_AGENT) == NBLK - 1);
    __syncthreads();
    if (!last) return;

    __shared__ float red[4];
    float s = 0.f;
    for (int r = t; r < TWO_N; r += 256) {
        float d = __hip_atomic_load(&den[r], __ATOMIC_RELAXED,
                                    __HIP_MEMORY_SCOPE_AGENT);
        s += logf(d);
    }
    for (int p = t; p < NB; p += 256) s -= 4.0f * pos[p];
    #pragma unroll
    for (int off = 32; off >= 1; off >>= 1) s += __shfl_xor(s, off, 64);
    if ((t & 63) == 0) red[t >> 6] = s;
    __syncthreads();
    if (t == 0)
        out[0] = (red[0] + red[1] + red[2] + red[3]) * (1.0f / (float)TWO_N);
}

// ---------------------------------------------------------------------------
extern "C" void kernel_launch(void* const* d_in, const int* in_sizes, int n_in,
                              void* d_out, int out_size, void* d_ws, size_t ws_size,
                              hipStream_t stream)
{
    const float* emb_i = (const float*)d_in[0];
    const float* emb_j = (const float*)d_in[1];
    float* out = (float*)d_out;

    __hip_bfloat16* zb = (__hip_bfloat16*)d_ws;           // 4096*256 bf16 = 2 MB
    float* den = (float*)((char*)d_ws + (size_t)TWO_N * DIM * sizeof(__hip_bfloat16));
    float* pos = den + TWO_N;                             // 2048 f32
    unsigned* cnt = (unsigned*)(pos + NB);                // 1 u32 ticket

    nrm_kernel<<<NB / 4, 256, 0, stream>>>(emb_i, emb_j, zb, pos, den, cnt);

    simexp_kernel<<<NBLK, 256, 0, stream>>>(zb, pos, den, cnt, out);
}